// Round 8
// baseline (162.388 us; speedup 1.0000x reference)
//
#include <hip/hip_runtime.h>
#include <math.h>

#define Ss 2048
#define Dd 1024
#define Pp 9
#define DMm 256
#define Tt 8192
#define EPSf 1e-5f
#define BAND 6e-3f       // fp64-rescue band for argmax ties

typedef __attribute__((ext_vector_type(8))) __bf16 bf16x8;
typedef __attribute__((ext_vector_type(4))) float f32x4;

#define GLOBAL_AS __attribute__((address_space(1)))
#define LDS_AS __attribute__((address_space(3)))

#define MAXT32 (Tt / 32 + Pp)   // 265: packed-grid upper bound, 32-token tiles

__device__ __forceinline__ unsigned short bf16rn(float f) {
  unsigned int u = __float_as_uint(f);
  unsigned int r = (u + 0x7fffu + ((u >> 16) & 1u)) >> 16;
  return (unsigned short)r;
}

__device__ __forceinline__ void gload16(const void* g, void* l) {
  __builtin_amdgcn_global_load_lds((const GLOBAL_AS unsigned int*)g,
                                   (LDS_AS unsigned int*)l, 16, 0, 0);
}

// swizzled LDS short-offset, BK=64 rows (8 x 16B slots/row)
#define KSW(r, sl) (((r) << 6) + ((((sl) ^ ((r) & 7))) << 3))

// ---------------------------------------------------------------- prep: mix -> bf16 + weight cvt/T + zero counts
__global__ __launch_bounds__(256) void k_prep(const float* __restrict__ x,
    const float* __restrict__ mk, unsigned short* __restrict__ xh,
    const float* __restrict__ W1, const float* __restrict__ W2,
    const float* __restrict__ Wo1,
    unsigned short* __restrict__ W1t, unsigned short* __restrict__ W2t,
    unsigned short* __restrict__ Wo1t, int* __restrict__ counts) {
  const int bid = blockIdx.x;
  if (bid < Tt) {
    if (bid == 0 && threadIdx.x < 64) counts[threadIdx.x] = 0;
    const int t = bid;
    const int s = t & (Ss - 1);
    const int d = threadIdx.x << 2;
    const float* xc = x + (size_t)t * Dd + d;
    float4 vb = *(const float4*)xc;
    float4 va = make_float4(0.f, 0.f, 0.f, 0.f);
    float4 vc = make_float4(0.f, 0.f, 0.f, 0.f);
    if (s > 0)      va = *(const float4*)(xc - Dd);
    if (s < Ss - 1) vc = *(const float4*)(xc + Dd);
    const float4 k0 = *(const float4*)(mk + d);
    const float4 k1 = *(const float4*)(mk + Dd + d);
    const float4 k2 = *(const float4*)(mk + 2 * Dd + d);
    float4 o;
    o.x = k0.x * va.x + k1.x * vb.x + k2.x * vc.x;
    o.y = k0.y * va.y + k1.y * vb.y + k2.y * vc.y;
    o.z = k0.z * va.z + k1.z * vb.z + k2.z * vc.z;
    o.w = k0.w * va.w + k1.w * vb.w + k2.w * vc.w;
    ushort4 h;
    h.x = bf16rn(o.x); h.y = bf16rn(o.y); h.z = bf16rn(o.z); h.w = bf16rn(o.w);
    *(ushort4*)(xh + (size_t)t * Dd + d) = h;
    return;
  }
  // weight convert+transpose: i in [0, 19*256)
  const int i = bid - Tt;
  const int z = i >> 8, rem = i & 255;
  const int bx = rem & 31, by = rem >> 5;
  const float* in; unsigned short* outp; int R, C, r0, c0;
  if (z < Pp)          { in = W1;  outp = W1t;  R = Dd;  C = DMm; r0 = bx * 32; c0 = by * 32; }
  else if (z < 2 * Pp) { in = W2;  outp = W2t;  R = DMm; C = Dd;  r0 = by * 32; c0 = bx * 32; }
  else                 { in = Wo1; outp = Wo1t; R = Dd;  C = DMm; r0 = bx * 32; c0 = by * 32; }
  const int zi = (z < Pp) ? z : ((z < 2 * Pp) ? z - Pp : 0);
  const size_t zo = (size_t)zi * R * C;
  __shared__ float tile[32][33];
  const int tr = threadIdx.x >> 3, tc = (threadIdx.x & 7) << 2;
  float4 v = *(const float4*)(in + zo + (size_t)(r0 + tr) * C + c0 + tc);
  tile[tr][tc] = v.x; tile[tr][tc + 1] = v.y; tile[tr][tc + 2] = v.z; tile[tr][tc + 3] = v.w;
  __syncthreads();
  ushort4 h;
  h.x = bf16rn(tile[tc + 0][tr]); h.y = bf16rn(tile[tc + 1][tr]);
  h.z = bf16rn(tile[tc + 2][tr]); h.w = bf16rn(tile[tc + 3][tr]);
  *(ushort4*)(outp + zo + (size_t)(c0 + tr) * R + r0 + tc) = h;
}

// ---------------------------------------------------------------- MFMA GEMM, 32x128 tile, BK=64, dbuf+vmcnt
// MODE 0: outf = tanh(acc+bias) (dense)   MODE 1: outh = bf16(acc+bias) (grouped)
template<int KTOT, int NTOT, int MODE, bool GROUPED>
__global__ __launch_bounds__(256) void k_gemm(
    const unsigned short* __restrict__ A,
    const unsigned short* __restrict__ Bt,
    const float* __restrict__ bias,
    float* __restrict__ outf, unsigned short* __restrict__ outh,
    const int* __restrict__ counts, const int* __restrict__ tokenlist) {
  int p = 0, ti = blockIdx.x, cnt = Tt;
  if (GROUPED) {
    for (p = 0; p < Pp; ++p) {
      cnt = counts[p];
      const int nt = (cnt + 31) >> 5;
      if (ti < nt) break;
      ti -= nt;
    }
    if (p == Pp) return;
  }
  const int tile0 = ti * 32;
  __shared__ int tl[32];
  __shared__ __align__(16) unsigned short As[2][32 * 64];   // 2 x 4 KB
  __shared__ __align__(16) unsigned short Bs[2][128 * 64];  // 2 x 16 KB
  const int tid = threadIdx.x;
  if (tid < 32) {
    const int li = tile0 + tid;
    if (GROUPED) tl[tid] = (li < cnt) ? tokenlist[p * Tt + li] : tokenlist[p * Tt];
    else         tl[tid] = li;
  }
  __syncthreads();
  const int w = tid >> 6, lane = tid & 63;
  const int fr = lane & 15, fs = lane >> 4;
  const int wr = w >> 1, wc = w & 1;
  const int n0 = blockIdx.y * 128;
  const unsigned short* Bp0 = Bt + (size_t)p * NTOT * KTOT + (size_t)n0 * KTOT;
  // staging: A 1 issue (u=tid), B 4 issues
  const int ua = tid, ra = ua >> 3, sa = (ua & 7) ^ (ra & 7);
  const unsigned short* srcA = A + (size_t)tl[ra] * KTOT + sa * 8;
  const unsigned short* srcB[4];
  #pragma unroll
  for (int i = 0; i < 4; ++i) {
    const int u = i * 256 + tid, r = u >> 3, sl = (u & 7) ^ (r & 7);
    srcB[i] = Bp0 + (size_t)r * KTOT + sl * 8;
  }
  const int ldsW = w * 512;
  int aoff[2], boff[4][2];
  #pragma unroll
  for (int kk = 0; kk < 2; ++kk) aoff[kk] = KSW(wr * 16 + fr, kk * 4 + fs);
  #pragma unroll
  for (int n = 0; n < 4; ++n)
    #pragma unroll
    for (int kk = 0; kk < 2; ++kk)
      boff[n][kk] = KSW(wc * 64 + n * 16 + fr, kk * 4 + fs);

#define STAGE(b, kb) do { \
    gload16(srcA + (kb), &As[b][0] + ldsW); \
    gload16(srcB[0] + (kb), &Bs[b][0] + ldsW); \
    gload16(srcB[1] + (kb), &Bs[b][0] + 2048 + ldsW); \
    gload16(srcB[2] + (kb), &Bs[b][0] + 4096 + ldsW); \
    gload16(srcB[3] + (kb), &Bs[b][0] + 6144 + ldsW); \
  } while (0)

  f32x4 acc[4] = {};
  const int NS = KTOT / 64;
  STAGE(0, 0);
  for (int s = 0; s < NS; ++s) {
    const int buf = s & 1;
    if (s + 1 < NS) {
      STAGE(buf ^ 1, (s + 1) * 64);
      asm volatile("s_waitcnt vmcnt(5)" ::: "memory");
    } else {
      asm volatile("s_waitcnt vmcnt(0)" ::: "memory");
    }
    __builtin_amdgcn_s_barrier();
    __builtin_amdgcn_sched_barrier(0);
    const unsigned short* Ab = &As[buf][0];
    const unsigned short* Bb_ = &Bs[buf][0];
    bf16x8 a[2], b[4][2];
    #pragma unroll
    for (int kk = 0; kk < 2; ++kk) a[kk] = *(const bf16x8*)&Ab[aoff[kk]];
    #pragma unroll
    for (int n = 0; n < 4; ++n)
      #pragma unroll
      for (int kk = 0; kk < 2; ++kk)
        b[n][kk] = *(const bf16x8*)&Bb_[boff[n][kk]];
    #pragma unroll
    for (int kk = 0; kk < 2; ++kk)
      #pragma unroll
      for (int n = 0; n < 4; ++n)
        acc[n] = __builtin_amdgcn_mfma_f32_16x16x32_bf16(a[kk], b[n][kk], acc[n], 0, 0, 0);
    __builtin_amdgcn_s_barrier();
  }
#undef STAGE

  // C/D: col = fr, row = fs*4 + j
  const float* bias_z = bias + (size_t)p * NTOT;
  #pragma unroll
  for (int j = 0; j < 4; ++j) {
    const int rr = wr * 16 + fs * 4 + j;
    const int li = tile0 + rr;
    if (GROUPED && li >= cnt) continue;
    const int t = tl[rr];
    #pragma unroll
    for (int n = 0; n < 4; ++n) {
      const int c = n0 + wc * 64 + n * 16 + fr;
      const float v = acc[n][j] + bias_z[c];
      if (MODE == 0) outf[(size_t)t * NTOT + c] = tanhf(v);
      else           outh[(size_t)t * NTOT + c] = bf16rn(v);
    }
  }
}

// ---------------------------------------------------------------- scores + argmax + flag + scatter (64 tokens/block)
__global__ __launch_bounds__(256) void k_score(const float* __restrict__ hidden,
    const float* __restrict__ Wo2, const float* __restrict__ bo2,
    int* __restrict__ idx, int* __restrict__ nflag, int* __restrict__ flagged,
    int* __restrict__ counts, int* __restrict__ tokenlist) {
  __shared__ float sW[DMm * Pp];
  __shared__ int lcnt[Pp], lbase[Pp];
  const int tid = threadIdx.x;
  for (int l = tid; l < DMm * Pp; l += 256) sW[l] = Wo2[l];
  if (tid < Pp) lcnt[tid] = 0;
  __syncthreads();
  const int wave = tid >> 6, lane = tid & 63;
  int tArr[16], pArr[16], sArr[16];
  #pragma unroll
  for (int it = 0; it < 16; ++it) {
    const int t = blockIdx.x * 64 + it * 4 + wave;
    const float4 h = *(const float4*)(hidden + (size_t)t * DMm + lane * 4);
    const int m = lane * 4;
    float part[Pp];
    #pragma unroll
    for (int pp = 0; pp < Pp; ++pp)
      part[pp] = h.x * sW[(m + 0) * Pp + pp] + h.y * sW[(m + 1) * Pp + pp]
               + h.z * sW[(m + 2) * Pp + pp] + h.w * sW[(m + 3) * Pp + pp];
    #pragma unroll
    for (int off = 32; off > 0; off >>= 1)
      #pragma unroll
      for (int pp = 0; pp < Pp; ++pp)
        part[pp] += __shfl_xor(part[pp], off);
    tArr[it] = -1;
    if (lane == 0) {
      float best = -1e30f, second = -1e30f;
      int bi = 0;
      #pragma unroll
      for (int pp = 0; pp < Pp; ++pp) {
        const float sc = part[pp] + bo2[pp];
        if (sc > best) { second = best; best = sc; bi = pp; }
        else if (sc > second) second = sc;
      }
      idx[t] = bi;
      if (best - second < BAND) {
        const int pos = atomicAdd(nflag, 1);
        flagged[pos] = t;            // rescue will scatter this token
      } else {
        tArr[it] = t; pArr[it] = bi;
        sArr[it] = atomicAdd(&lcnt[bi], 1);
      }
    }
  }
  __syncthreads();
  if (tid < Pp) lbase[tid] = atomicAdd(&counts[tid], lcnt[tid]);
  __syncthreads();
  #pragma unroll
  for (int it = 0; it < 16; ++it)
    if (tArr[it] >= 0)
      tokenlist[pArr[it] * Tt + lbase[pArr[it]] + sArr[it]] = tArr[it];
}

// ---------------------------------------------------------------- fp64 rescue (+ scatter of flagged tokens)
__global__ __launch_bounds__(256) void k_rescue(const float* __restrict__ x,
    const float* __restrict__ mk,
    const float* __restrict__ Wo1, const float* __restrict__ bo1,
    const float* __restrict__ Wo2, const float* __restrict__ bo2,
    const int* __restrict__ nflag, const int* __restrict__ flagged,
    int* __restrict__ idx, int* __restrict__ counts, int* __restrict__ tokenlist) {
  __shared__ double sx[Dd];
  __shared__ double th[DMm];
  __shared__ double red[4][12];
  const int nf = *nflag;
  const int tid = threadIdx.x;
  const int wv = tid >> 6, ln = tid & 63;
  for (int f = blockIdx.x; f < nf; f += gridDim.x) {
    const int t = flagged[f];
    const int s = t & (Ss - 1);
    for (int l = tid; l < Dd; l += 256) {
      const double xa = (s > 0)      ? (double)x[(size_t)(t - 1) * Dd + l] : 0.0;
      const double xb =                (double)x[(size_t)t * Dd + l];
      const double xc = (s < Ss - 1) ? (double)x[(size_t)(t + 1) * Dd + l] : 0.0;
      sx[l] = (double)mk[l] * xa + (double)mk[Dd + l] * xb + (double)mk[2 * Dd + l] * xc;
    }
    __syncthreads();
    {
      double a0 = 0, a1 = 0, a2 = 0, a3 = 0;
      const float* wcol = Wo1 + tid;
      for (int d = 0; d < Dd; d += 4) {
        a0 += sx[d + 0] * (double)wcol[(size_t)(d + 0) * DMm];
        a1 += sx[d + 1] * (double)wcol[(size_t)(d + 1) * DMm];
        a2 += sx[d + 2] * (double)wcol[(size_t)(d + 2) * DMm];
        a3 += sx[d + 3] * (double)wcol[(size_t)(d + 3) * DMm];
      }
      th[tid] = tanh(((a0 + a1) + (a2 + a3)) + (double)bo1[tid]);
    }
    __syncthreads();
    double pr[Pp];
    const double tv = th[tid];
    #pragma unroll
    for (int p = 0; p < Pp; ++p) pr[p] = tv * (double)Wo2[tid * Pp + p];
    #pragma unroll
    for (int off = 32; off > 0; off >>= 1)
      #pragma unroll
      for (int p = 0; p < Pp; ++p) pr[p] += __shfl_xor(pr[p], off);
    if (ln == 0) {
      #pragma unroll
      for (int p = 0; p < Pp; ++p) red[wv][p] = pr[p];
    }
    __syncthreads();
    if (tid == 0) {
      double best = -1e300; int bi = 0;
      #pragma unroll
      for (int p = 0; p < Pp; ++p) {
        const double sv = red[0][p] + red[1][p] + red[2][p] + red[3][p] + (double)bo2[p];
        if (sv > best) { best = sv; bi = p; }
      }
      idx[t] = bi;
      const int pos = atomicAdd(&counts[bi], 1);
      tokenlist[bi * Tt + pos] = t;
    }
    __syncthreads();
  }
}

// ---------------------------------------------------------------- fused GEMM2 + residual + LayerNorm
// block: 32 tokens x full 1024 cols; K=256; acc in registers; B via dbuf LDS
__global__ __launch_bounds__(256) void k_g2ln(
    const unsigned short* __restrict__ h1,
    const unsigned short* __restrict__ W2t,
    const float* __restrict__ b2,
    const float* __restrict__ x,
    const float* __restrict__ gamma, const float* __restrict__ beta,
    const int* __restrict__ counts, const int* __restrict__ tokenlist,
    float* __restrict__ out) {
  int p = 0, ti = blockIdx.x, cnt = 0;
  for (p = 0; p < Pp; ++p) {
    cnt = counts[p];
    const int nt = (cnt + 31) >> 5;
    if (ti < nt) break;
    ti -= nt;
  }
  if (p == Pp) return;
  const int tile0 = ti * 32;
  __shared__ int tl[32];
  __shared__ __align__(16) unsigned short Bs[2][64 * 256];  // 2 x 32 KB
  __shared__ float sS[32][2], sQ[32][2];
  const int tid = threadIdx.x;
  if (tid < 32) {
    const int li = tile0 + tid;
    tl[tid] = (li < cnt) ? tokenlist[p * Tt + li] : tokenlist[p * Tt];
  }
  __syncthreads();
  const int w = tid >> 6, lane = tid & 63;
  const int fr = lane & 15, fs = lane >> 4;
  const int th = w >> 1, ch = w & 1;
  // A (h1 rows) in registers
  const unsigned short* arow = h1 + (size_t)tl[th * 16 + fr] * DMm;
  bf16x8 pa[8];
  #pragma unroll
  for (int ks = 0; ks < 8; ++ks) pa[ks] = *(const bf16x8*)(arow + ks * 32 + fs * 8);
  // B staging: per chunk 64 cols x 256 k = 2048 units of 16B, 8 issues
  const unsigned short* Bbase = W2t + (size_t)p * Dd * DMm;
  int srow[8], ssl[8];
  #pragma unroll
  for (int i = 0; i < 8; ++i) {
    const int u = i * 256 + tid;
    srow[i] = u >> 5;
    ssl[i] = ((u & 31) ^ (srow[i] & 31)) << 3;
  }
#define STG(b, cb) do { \
    unsigned short* L = &Bs[b][0]; \
    _Pragma("unroll") \
    for (int i = 0; i < 8; ++i) \
      gload16(Bbase + (size_t)((cb) + srow[i]) * DMm + ssl[i], L + (i * 256 + tid) * 8); \
  } while (0)

  f32x4 acc[16][2] = {};
  STG(0, 0);
  STG(1, 64);
  #pragma unroll
  for (int c = 0; c < 16; ++c) {
    const int buf = c & 1;
    if (c < 15) asm volatile("s_waitcnt vmcnt(8)" ::: "memory");
    else        asm volatile("s_waitcnt vmcnt(0)" ::: "memory");
    __builtin_amdgcn_s_barrier();
    __builtin_amdgcn_sched_barrier(0);
    #pragma unroll
    for (int ks = 0; ks < 8; ++ks) {
      #pragma unroll
      for (int nf = 0; nf < 2; ++nf) {
        const int rc = ch * 32 + nf * 16 + fr;
        const bf16x8 bfrag = *(const bf16x8*)&Bs[buf][rc * 256 + ((((ks * 4 + fs)) ^ (rc & 31)) << 3)];
        acc[c][nf] = __builtin_amdgcn_mfma_f32_16x16x32_bf16(pa[ks], bfrag, acc[c][nf], 0, 0, 0);
      }
    }
    __builtin_amdgcn_s_barrier();
    if (c + 2 < 16) STG(buf, (c + 2) * 64);
  }
#undef STG

  // epilogue: + b2 + x, stats, LN, write
  const float* b2p = b2 + (size_t)p * Dd;
  int tok[4];
  #pragma unroll
  for (int j = 0; j < 4; ++j) tok[j] = tl[th * 16 + fs * 4 + j];
  float s[4] = {}, q[4] = {};
  #pragma unroll
  for (int c = 0; c < 16; ++c) {
    #pragma unroll
    for (int nf = 0; nf < 2; ++nf) {
      const int col = c * 64 + ch * 32 + nf * 16 + fr;
      const float bv = b2p[col];
      #pragma unroll
      for (int j = 0; j < 4; ++j) {
        const float h = acc[c][nf][j] + bv + x[(size_t)tok[j] * Dd + col];
        acc[c][nf][j] = h;
        s[j] += h; q[j] += h * h;
      }
    }
  }
  #pragma unroll
  for (int off = 1; off < 16; off <<= 1)
    #pragma unroll
    for (int j = 0; j < 4; ++j) {
      s[j] += __shfl_xor(s[j], off);
      q[j] += __shfl_xor(q[j], off);
    }
  if (fr == 0) {
    #pragma unroll
    for (int j = 0; j < 4; ++j) {
      sS[th * 16 + fs * 4 + j][ch] = s[j];
      sQ[th * 16 + fs * 4 + j][ch] = q[j];
    }
  }
  __syncthreads();
  float mu[4], inv[4];
  #pragma unroll
  for (int j = 0; j < 4; ++j) {
    const int r = th * 16 + fs * 4 + j;
    const float S = sS[r][0] + sS[r][1];
    const float Q = sQ[r][0] + sQ[r][1];
    mu[j] = S * (1.f / Dd);
    const float var = Q * (1.f / Dd) - mu[j] * mu[j];
    inv[j] = rsqrtf(var + EPSf);
  }
  #pragma unroll
  for (int c = 0; c < 16; ++c) {
    #pragma unroll
    for (int nf = 0; nf < 2; ++nf) {
      const int col = c * 64 + ch * 32 + nf * 16 + fr;
      const float g = gamma[col], bt = beta[col];
      #pragma unroll
      for (int j = 0; j < 4; ++j) {
        const int li = tile0 + th * 16 + fs * 4 + j;
        if (li >= cnt) continue;
        out[(size_t)tok[j] * Dd + col] = (acc[c][nf][j] - mu[j]) * inv[j] * g + bt;
      }
    }
  }
}

// ----------------------------------------------------------------
extern "C" void kernel_launch(void* const* d_in, const int* in_sizes, int n_in,
                              void* d_out, int out_size, void* d_ws, size_t ws_size,
                              hipStream_t stream) {
  (void)in_sizes; (void)n_in; (void)out_size; (void)ws_size;
  const float* x     = (const float*)d_in[0];
  const float* mk    = (const float*)d_in[1];
  const float* W1    = (const float*)d_in[2];
  const float* b1    = (const float*)d_in[3];
  const float* W2    = (const float*)d_in[4];
  const float* b2    = (const float*)d_in[5];
  const float* Wo1   = (const float*)d_in[6];
  const float* bo1   = (const float*)d_in[7];
  const float* Wo2   = (const float*)d_in[8];
  const float* bo2   = (const float*)d_in[9];
  const float* gamma = (const float*)d_in[10];
  const float* beta  = (const float*)d_in[11];
  float* out = (float*)d_out;

  size_t off = 0;
  auto alloc = [&](size_t bytes) -> void* {
    void* p = (char*)d_ws + off;
    off += (bytes + 255) & ~(size_t)255;
    return p;
  };
  unsigned short* xm_h   = (unsigned short*)alloc((size_t)Tt * Dd * 2);
  float*          hidden = (float*)alloc((size_t)Tt * DMm * 4);
  unsigned short* h1     = (unsigned short*)hidden;  // alias: hidden dead before h1 written
  unsigned short* W1t    = (unsigned short*)alloc((size_t)Pp * Dd * DMm * 2);
  unsigned short* W2t    = (unsigned short*)alloc((size_t)Pp * DMm * Dd * 2);
  unsigned short* Wo1t   = (unsigned short*)alloc((size_t)Dd * DMm * 2);
  int* idx      = (int*)alloc(Tt * 4);
  int* counts   = (int*)alloc(64 * 4);
  int* nflag    = counts + 16;
  int* flagged  = (int*)alloc(Tt * 4);
  int* tokenlist = (int*)alloc((size_t)Pp * Tt * 4);

  k_prep<<<Tt + (2 * Pp + 1) * 256, 256, 0, stream>>>(
      x, mk, xm_h, W1, W2, Wo1, W1t, W2t, Wo1t, counts);

  k_gemm<Dd, DMm, 0, false><<<dim3(Tt / 32, DMm / 128), 256, 0, stream>>>(
      xm_h, Wo1t, bo1, hidden, nullptr, nullptr, nullptr);
  k_score<<<Tt / 64, 256, 0, stream>>>(hidden, Wo2, bo2, idx, nflag, flagged,
                                       counts, tokenlist);
  k_rescue<<<256, 256, 0, stream>>>(x, mk, Wo1, bo1, Wo2, bo2, nflag, flagged,
                                    idx, counts, tokenlist);

  k_gemm<Dd, DMm, 1, true><<<dim3(MAXT32, DMm / 128), 256, 0, stream>>>(
      xm_h, W1t, b1, nullptr, h1, counts, tokenlist);
  k_g2ln<<<MAXT32, 256, 0, stream>>>(h1, W2t, b2, x, gamma, beta,
                                     counts, tokenlist, out);
}